// Round 4
// baseline (990.848 us; speedup 1.0000x reference)
//
#include <hip/hip_runtime.h>

#define NN 100000
#define NE 1600000
#define FF 128
#define KK 25000
#define NB ((NN + 255) / 256)   // 391 blocks of 256 over nodes
#define GEMM_TM 64
#define GEMM_GRID ((NN + GEMM_TM - 1) / GEMM_TM)

// ---------- bf16 helpers (packed pairs in a uint) ----------
__device__ __forceinline__ unsigned short f2b(float f) {
  unsigned u = __float_as_uint(f);
  u += 0x7FFFu + ((u >> 16) & 1u);  // round-to-nearest-even
  return (unsigned short)(u >> 16);
}
__device__ __forceinline__ unsigned pack2(float lo, float hi) {
  return (unsigned)f2b(lo) | ((unsigned)f2b(hi) << 16);
}

// ---------- top-k key ----------
__device__ __forceinline__ unsigned long long topk_key(float s, unsigned i) {
  // score is sigmoid output (>=0) so float bits are monotonic in value.
  return (((unsigned long long)__float_as_uint(s)) << 32) |
         (unsigned long long)(0xFFFFFFFFu - i);
}

// ---------- CSR build ----------
__global__ __launch_bounds__(256) void k_degree(const int* __restrict__ tgt,
                                                int* __restrict__ cnt) {
  int e = blockIdx.x * 256 + threadIdx.x;
  if (e < NE) atomicAdd(&cnt[tgt[e]], 1);
}

__global__ __launch_bounds__(256) void k_blocksum(const int* __restrict__ cnt,
                                                  int* __restrict__ bsum) {
  __shared__ int s[256];
  int i = blockIdx.x * 256 + threadIdx.x;
  s[threadIdx.x] = (i < NN) ? cnt[i] : 0;
  __syncthreads();
  for (int off = 128; off > 0; off >>= 1) {
    if (threadIdx.x < off) s[threadIdx.x] += s[threadIdx.x + off];
    __syncthreads();
  }
  if (threadIdx.x == 0) bsum[blockIdx.x] = s[0];
}

__global__ __launch_bounds__(512) void k_scan_bsum(int* __restrict__ bsum) {
  __shared__ int s[512];
  int t = threadIdx.x;
  int own = (t < NB) ? bsum[t] : 0;
  s[t] = own;
  __syncthreads();
  for (int off = 1; off < 512; off <<= 1) {
    int v = (t >= off) ? s[t - off] : 0;
    __syncthreads();
    s[t] += v;
    __syncthreads();
  }
  if (t < NB) bsum[t] = s[t] - own;  // exclusive
}

__global__ __launch_bounds__(256) void k_scan_final(const int* __restrict__ cnt,
                                                    const int* __restrict__ bsum,
                                                    int* __restrict__ offsets) {
  __shared__ int s[256];
  int i = blockIdx.x * 256 + threadIdx.x;
  int own = (i < NN) ? cnt[i] : 0;
  s[threadIdx.x] = own;
  __syncthreads();
  for (int off = 1; off < 256; off <<= 1) {
    int v = (threadIdx.x >= off) ? s[threadIdx.x - off] : 0;
    __syncthreads();
    s[threadIdx.x] += v;
    __syncthreads();
  }
  if (i < NN) offsets[i] = bsum[blockIdx.x] + s[threadIdx.x] - own;
  if (i == NN - 1) offsets[NN] = bsum[blockIdx.x] + s[threadIdx.x];
}

__global__ __launch_bounds__(256) void k_fill(const int* __restrict__ src,
                                              const int* __restrict__ tgt,
                                              const int* __restrict__ offsets,
                                              int* __restrict__ cursor,
                                              int* __restrict__ csr_src) {
  int e = blockIdx.x * 256 + threadIdx.x;
  if (e < NE) {
    int t = tgt[e];
    int p = atomicAdd(&cursor[t], 1);
    csr_src[offsets[t] + p] = src[e];
  }
}

// ---------- f32 mean aggregation (1 wave per node), order-preserving unroll x4 ----------
__global__ __launch_bounds__(256) void k_agg(const float* __restrict__ vals,
                                             const int* __restrict__ csr,
                                             const int* __restrict__ offsets,
                                             float* __restrict__ outv) {
  int w = threadIdx.x >> 6;
  int lane = threadIdx.x & 63;
  int node = blockIdx.x * 4 + w;
  if (node >= NN) return;
  int beg = offsets[node];
  int end = offsets[node + 1];
  float ax = 0.f, ay = 0.f;
  int e = beg;
  int e4 = beg + ((end - beg) & ~3);
  for (; e < e4; e += 4) {
    int j0 = csr[e], j1 = csr[e + 1], j2 = csr[e + 2], j3 = csr[e + 3];
    float2 v0 = *reinterpret_cast<const float2*>(&vals[(size_t)j0 * FF + lane * 2]);
    float2 v1 = *reinterpret_cast<const float2*>(&vals[(size_t)j1 * FF + lane * 2]);
    float2 v2 = *reinterpret_cast<const float2*>(&vals[(size_t)j2 * FF + lane * 2]);
    float2 v3 = *reinterpret_cast<const float2*>(&vals[(size_t)j3 * FF + lane * 2]);
    ax += v0.x; ay += v0.y;
    ax += v1.x; ay += v1.y;
    ax += v2.x; ay += v2.y;
    ax += v3.x; ay += v3.y;
  }
  for (; e < end; ++e) {
    int j = csr[e];
    float2 v = *reinterpret_cast<const float2*>(&vals[(size_t)j * FF + lane * 2]);
    ax += v.x; ay += v.y;
  }
  int deg = end - beg;
  float inv = 1.0f / (float)(deg > 0 ? deg : 1);
  float2 o;
  o.x = ax * inv;
  o.y = ay * inv;
  *reinterpret_cast<float2*>(&outv[(size_t)node * FF + lane * 2]) = o;
}

// ---------- bf16 mean aggregation (1 wave per node), order-preserving unroll x4 ----------
template <bool GATED>
__global__ __launch_bounds__(256) void k_agg_bf(const unsigned* __restrict__ vals,
                                                const int* __restrict__ csr,
                                                const int* __restrict__ offsets,
                                                const float* __restrict__ sel,
                                                unsigned* __restrict__ outv) {
  int w = threadIdx.x >> 6;
  int lane = threadIdx.x & 63;
  int node = blockIdx.x * 4 + w;
  if (node >= NN) return;
  int beg = offsets[node];
  int end = offsets[node + 1];
  float ax = 0.f, ay = 0.f;
  int e = beg;
  int e4 = beg + ((end - beg) & ~3);
  for (; e < e4; e += 4) {
    int j0 = csr[e], j1 = csr[e + 1], j2 = csr[e + 2], j3 = csr[e + 3];
    unsigned u0 = (!GATED || sel[j0] != 0.f) ? vals[(size_t)j0 * (FF / 2) + lane] : 0u;
    unsigned u1 = (!GATED || sel[j1] != 0.f) ? vals[(size_t)j1 * (FF / 2) + lane] : 0u;
    unsigned u2 = (!GATED || sel[j2] != 0.f) ? vals[(size_t)j2 * (FF / 2) + lane] : 0u;
    unsigned u3 = (!GATED || sel[j3] != 0.f) ? vals[(size_t)j3 * (FF / 2) + lane] : 0u;
    ax += __uint_as_float(u0 << 16); ay += __uint_as_float(u0 & 0xFFFF0000u);
    ax += __uint_as_float(u1 << 16); ay += __uint_as_float(u1 & 0xFFFF0000u);
    ax += __uint_as_float(u2 << 16); ay += __uint_as_float(u2 & 0xFFFF0000u);
    ax += __uint_as_float(u3 << 16); ay += __uint_as_float(u3 & 0xFFFF0000u);
  }
  for (; e < end; ++e) {
    int j = csr[e];
    unsigned u = (!GATED || sel[j] != 0.f) ? vals[(size_t)j * (FF / 2) + lane] : 0u;
    ax += __uint_as_float(u << 16); ay += __uint_as_float(u & 0xFFFF0000u);
  }
  int deg = end - beg;
  float inv = 1.0f / (float)(deg > 0 ? deg : 1);
  outv[(size_t)node * (FF / 2) + lane] = pack2(ax * inv, ay * inv);
}

// ---------- register-blocked GEMM: [NN,128] x [128,128] f32, W fully in LDS ----------
// Block: 256 threads -> 64 rows x 128 cols. Thread tile 4 rows x 8 cols.
// LDS: Ws[128][128] (64 KB) + As[64][132] (33 KB, pad 4 -> 2-way-only bank aliasing).
// DUAL: second pass restages W2/A2 into same LDS, accumulators stay in registers.
// EPI 0: out = A@W (+ A2@W2) + bias
// EPI 1: g = A@W + bias; v = sel ? aux*score : g; out = relu(v); obf = packed bf16(out)
// EPI 2: g = A@W + bias; out = sel ? aux : g
template <int EPI, bool DUAL, bool ABF16>
__global__ __launch_bounds__(256) void k_gemm2(const void* __restrict__ Araw,
                                               const float* __restrict__ W,
                                               const float* __restrict__ A2,
                                               const float* __restrict__ W2,
                                               const float* __restrict__ bias,
                                               const float* __restrict__ aux,
                                               const float* __restrict__ score,
                                               const float* __restrict__ sel,
                                               float* __restrict__ outv,
                                               unsigned* __restrict__ obf) {
  __shared__ float Ws[128 * 128];
  __shared__ float As[GEMM_TM * 132];
  const int tid = threadIdx.x;
  const int r0 = blockIdx.x * GEMM_TM;
  const int cg = tid & 15;   // 16 col groups x 8 cols
  const int rg = tid >> 4;   // 16 row groups x 4 rows
  const int ca = cg * 8;

  float acc[4][8];
#pragma unroll
  for (int r = 0; r < 4; ++r)
#pragma unroll
    for (int j = 0; j < 8; ++j) acc[r][j] = 0.f;

  auto stage_w = [&](const float* Wsrc) {
    const float4* Wg4 = (const float4*)Wsrc;
#pragma unroll
    for (int i = 0; i < 16; ++i) {
      int idx = tid + i * 256;  // 4096 float4s
      *(float4*)&Ws[idx * 4] = Wg4[idx];
    }
  };
  auto stage_a_f32 = [&](const float* Asrc) {
    const float4* Ag4 = (const float4*)Asrc;
#pragma unroll
    for (int i = 0; i < 8; ++i) {
      int idx = tid + i * 256;  // 2048 float4s = 64 rows x 32
      int r = idx >> 5, c4 = idx & 31;
      int gr = r0 + r;
      float4 v = make_float4(0.f, 0.f, 0.f, 0.f);
      if (gr < NN) v = Ag4[(size_t)gr * 32 + c4];
      *(float4*)&As[r * 132 + c4 * 4] = v;
    }
  };
  auto stage_a_bf16 = [&](const unsigned* Asrc) {
#pragma unroll
    for (int i = 0; i < 16; ++i) {
      int idx = tid + i * 256;  // 4096 uints = 64 rows x 64
      int r = idx >> 6, cu = idx & 63;
      int gr = r0 + r;
      unsigned u = (gr < NN) ? Asrc[(size_t)gr * 64 + cu] : 0u;
      float2 f;
      f.x = __uint_as_float(u << 16);
      f.y = __uint_as_float(u & 0xFFFF0000u);
      *(float2*)&As[r * 132 + cu * 2] = f;
    }
  };
  auto compute = [&]() {
#pragma unroll 4
    for (int k = 0; k < 128; k += 2) {
      float2 a0 = *(const float2*)&As[(rg * 4 + 0) * 132 + k];
      float2 a1 = *(const float2*)&As[(rg * 4 + 1) * 132 + k];
      float2 a2 = *(const float2*)&As[(rg * 4 + 2) * 132 + k];
      float2 a3 = *(const float2*)&As[(rg * 4 + 3) * 132 + k];
      float4 w00 = *(const float4*)&Ws[k * 128 + ca];
      float4 w01 = *(const float4*)&Ws[k * 128 + ca + 4];
      float4 w10 = *(const float4*)&Ws[(k + 1) * 128 + ca];
      float4 w11 = *(const float4*)&Ws[(k + 1) * 128 + ca + 4];
      float ak0[4] = {a0.x, a1.x, a2.x, a3.x};
      float ak1[4] = {a0.y, a1.y, a2.y, a3.y};
      float wv0[8] = {w00.x, w00.y, w00.z, w00.w, w01.x, w01.y, w01.z, w01.w};
      float wv1[8] = {w10.x, w10.y, w10.z, w10.w, w11.x, w11.y, w11.z, w11.w};
#pragma unroll
      for (int r = 0; r < 4; ++r)
#pragma unroll
        for (int j = 0; j < 8; ++j)
          acc[r][j] = fmaf(ak1[r], wv1[j], fmaf(ak0[r], wv0[j], acc[r][j]));
    }
  };

  stage_w(W);
  if constexpr (ABF16) stage_a_bf16((const unsigned*)Araw);
  else stage_a_f32((const float*)Araw);
  __syncthreads();
  compute();
  if constexpr (DUAL) {
    __syncthreads();
    stage_w(W2);
    stage_a_f32(A2);
    __syncthreads();
    compute();
  }

  float bs[8];
#pragma unroll
  for (int j = 0; j < 8; ++j) bs[j] = bias[ca + j];

#pragma unroll
  for (int r = 0; r < 4; ++r) {
    int gi = r0 + rg * 4 + r;
    if (gi >= NN) continue;
    size_t base = (size_t)gi * FF + ca;
    float v[8];
    if (EPI == 0) {
#pragma unroll
      for (int j = 0; j < 8; ++j) v[j] = acc[r][j] + bs[j];
    } else if (EPI == 1) {
      float se = sel[gi];
      float sc = score[gi];
      float4 x0 = *(const float4*)&aux[base];
      float4 x1 = *(const float4*)&aux[base + 4];
      float av[8] = {x0.x, x0.y, x0.z, x0.w, x1.x, x1.y, x1.z, x1.w};
#pragma unroll
      for (int j = 0; j < 8; ++j) {
        float g = acc[r][j] + bs[j];
        float t = (se != 0.f) ? av[j] * sc : g;
        v[j] = fmaxf(t, 0.f);
      }
      uint4 pk;
      pk.x = pack2(v[0], v[1]);
      pk.y = pack2(v[2], v[3]);
      pk.z = pack2(v[4], v[5]);
      pk.w = pack2(v[6], v[7]);
      *(uint4*)&obf[(size_t)gi * (FF / 2) + cg * 4] = pk;
    } else {
      float se = sel[gi];
      float4 x0 = *(const float4*)&aux[base];
      float4 x1 = *(const float4*)&aux[base + 4];
      float av[8] = {x0.x, x0.y, x0.z, x0.w, x1.x, x1.y, x1.z, x1.w};
#pragma unroll
      for (int j = 0; j < 8; ++j) {
        float g = acc[r][j] + bs[j];
        v[j] = (se != 0.f) ? av[j] : g;
      }
    }
    float4 o0 = make_float4(v[0], v[1], v[2], v[3]);
    float4 o1 = make_float4(v[4], v[5], v[6], v[7]);
    *(float4*)&outv[base] = o0;
    *(float4*)&outv[base + 4] = o1;
  }
}

// ---------- scorer ----------
__global__ __launch_bounds__(256) void k_score(const float* __restrict__ h,
                                               const float* __restrict__ wsc,
                                               const float* __restrict__ bsc,
                                               float* __restrict__ score) {
  int lane = threadIdx.x & 63;
  int w = threadIdx.x >> 6;
  int i = blockIdx.x * 4 + w;
  if (i >= NN) return;
  float2 a = *reinterpret_cast<const float2*>(&h[(size_t)i * FF + lane * 2]);
  float2 ww = *reinterpret_cast<const float2*>(&wsc[lane * 2]);
  float v = a.x * ww.x + a.y * ww.y;
#pragma unroll
  for (int off = 32; off > 0; off >>= 1) v += __shfl_xor(v, off, 64);
  if (lane == 0) {
    float t = v + bsc[0];
    score[i] = 1.0f / (1.0f + expf(-t));
  }
}

// ---------- exact top-K: 8-round radix select on 64-bit composite key ----------
__global__ void k_init_state(unsigned* state) {
  state[0] = 0u;  // prefix hi
  state[1] = 0u;  // prefix lo
  state[2] = KK;  // remaining rank
}

__global__ __launch_bounds__(256) void k_hist(const float* __restrict__ score,
                                              const unsigned* __restrict__ state,
                                              unsigned* __restrict__ hist,
                                              int bits_fixed) {
  __shared__ unsigned lh[256];
  for (int i = threadIdx.x; i < 256; i += 256) lh[i] = 0;
  __syncthreads();
  unsigned long long prefix =
      (((unsigned long long)state[0]) << 32) | (unsigned long long)state[1];
  int i = blockIdx.x * 256 + threadIdx.x;
  if (i < NN) {
    unsigned long long key = topk_key(score[i], (unsigned)i);
    bool ok = (bits_fixed == 0) ? true : (((key ^ prefix) >> (64 - bits_fixed)) == 0ull);
    if (ok) {
      unsigned b = (unsigned)((key >> (56 - bits_fixed)) & 0xFFull);
      atomicAdd(&lh[b], 1u);
    }
  }
  __syncthreads();
  for (int i2 = threadIdx.x; i2 < 256; i2 += 256)
    if (lh[i2]) atomicAdd(&hist[i2], lh[i2]);
}

__global__ __launch_bounds__(256) void k_select_round(unsigned* __restrict__ state,
                                                      unsigned* __restrict__ hist,
                                                      int bits_fixed) {
  __shared__ unsigned h[256];
  int t = threadIdx.x;
  h[t] = hist[t];
  hist[t] = 0;  // ready for next round
  __syncthreads();
  if (t == 0) {
    unsigned rem = state[2];
    unsigned long long prefix =
        (((unsigned long long)state[0]) << 32) | (unsigned long long)state[1];
    unsigned cum = 0;
    int bstar = 0;
    for (int b = 255; b >= 0; --b) {
      unsigned c = h[b];
      if (cum + c >= rem) { bstar = b; break; }
      cum += c;
    }
    rem -= cum;
    prefix |= ((unsigned long long)bstar) << (56 - bits_fixed);
    state[0] = (unsigned)(prefix >> 32);
    state[1] = (unsigned)(prefix & 0xFFFFFFFFull);
    state[2] = rem;
  }
}

__global__ __launch_bounds__(256) void k_mask(const float* __restrict__ score,
                                              const unsigned* __restrict__ state,
                                              float* __restrict__ sel) {
  int i = blockIdx.x * 256 + threadIdx.x;
  if (i >= NN) return;
  unsigned long long T =
      (((unsigned long long)state[0]) << 32) | (unsigned long long)state[1];
  unsigned long long key = topk_key(score[i], (unsigned)i);
  sel[i] = (key >= T) ? 1.0f : 0.0f;
}

// ---------- pack gated z rows (selected only) to bf16 ----------
__global__ __launch_bounds__(256) void k_gate_zg(const float* __restrict__ h,
                                                 const float* __restrict__ score,
                                                 const float* __restrict__ sel,
                                                 unsigned* __restrict__ zg) {
  int w = threadIdx.x >> 6;
  int lane = threadIdx.x & 63;
  int node = blockIdx.x * 4 + w;
  if (node >= NN) return;
  if (sel[node] == 0.f) return;
  float s = score[node];
  float2 v = *reinterpret_cast<const float2*>(&h[(size_t)node * FF + lane * 2]);
  zg[(size_t)node * (FF / 2) + lane] = pack2(v.x * s, v.y * s);
}

// ---------- launch ----------
extern "C" void kernel_launch(void* const* d_in, const int* in_sizes, int n_in,
                              void* d_out, int out_size, void* d_ws, size_t ws_size,
                              hipStream_t stream) {
  const float* x = (const float*)d_in[0];
  const int* src = (const int*)d_in[1];
  const int* tgt = (const int*)d_in[2];
  const float* W_self = (const float*)d_in[3];
  const float* W_neigh = (const float*)d_in[4];
  const float* b_pack = (const float*)d_in[5];
  const float* w_score = (const float*)d_in[6];
  const float* b_score = (const float*)d_in[7];
  const float* W_u1 = (const float*)d_in[8];
  const float* b_u1 = (const float*)d_in[9];
  const float* W_u2 = (const float*)d_in[10];
  const float* b_u2 = (const float*)d_in[11];
  float* out = (float*)d_out;

  char* ws = (char*)d_ws;
  size_t off = 0;
  auto alloc = [&](size_t bytes) -> char* {
    char* p = ws + off;
    off += (bytes + 255) & ~(size_t)255;
    return p;
  };
  int* cnt = (int*)alloc((size_t)NN * 4);
  int* offsets = (int*)alloc((size_t)(NN + 1) * 4);
  int* cursor = (int*)alloc((size_t)NN * 4);
  int* csr = (int*)alloc((size_t)NE * 4);
  float* score = (float*)alloc((size_t)NN * 4);
  float* sel = (float*)alloc((size_t)NN * 4);
  int* bsum = (int*)alloc(512 * 4);
  unsigned* hist = (unsigned*)alloc(256 * 4);
  unsigned* state = (unsigned*)alloc(64);
  float* aggF = (float*)alloc((size_t)NN * FF * 4);  // 51.2 MB, reused after gemm0:
  unsigned* zdbf = (unsigned*)aggF;                   //   first half: z-bf16 then d-bf16
  unsigned* aggBF = (unsigned*)(aggF + (size_t)NN * (FF / 2));  // second half: bf16 agg out
  float* bufB = out;  // h, then d, live in d_out (element-wise in-place safe)

  hipMemsetAsync(cnt, 0, (size_t)NN * 4, stream);
  hipMemsetAsync(cursor, 0, (size_t)NN * 4, stream);
  hipMemsetAsync(hist, 0, 256 * 4, stream);
  k_init_state<<<1, 1, 0, stream>>>(state);

  // CSR by target
  k_degree<<<(NE + 255) / 256, 256, 0, stream>>>(tgt, cnt);
  k_blocksum<<<NB, 256, 0, stream>>>(cnt, bsum);
  k_scan_bsum<<<1, 512, 0, stream>>>(bsum);
  k_scan_final<<<NB, 256, 0, stream>>>(cnt, bsum, offsets);
  k_fill<<<(NE + 255) / 256, 256, 0, stream>>>(src, tgt, offsets, cursor, csr);

  // ---- compress (all f32: score path is selection-critical) ----
  k_agg<<<NN / 4, 256, 0, stream>>>(x, csr, offsets, aggF);
  k_gemm2<0, true, false><<<GEMM_GRID, 256, 0, stream>>>(aggF, W_neigh, x, W_self,
                                                         b_pack, nullptr, nullptr,
                                                         nullptr, bufB, nullptr);
  k_score<<<NN / 4, 256, 0, stream>>>(bufB, w_score, b_score, score);

  // exact top-K (radix select, no host sync)
  for (int r = 0; r < 8; ++r) {
    k_hist<<<NB, 256, 0, stream>>>(score, state, hist, 8 * r);
    k_select_round<<<1, 256, 0, stream>>>(state, hist, 8 * r);
  }
  k_mask<<<NB, 256, 0, stream>>>(score, state, sel);

  // ---- decompress (bf16 gathers; selected rows stay f32) ----
  // diffusion 1: zg rows written only where selected; gated agg skips others
  k_gate_zg<<<NN / 4, 256, 0, stream>>>(bufB, score, sel, zdbf);
  k_agg_bf<true><<<NN / 4, 256, 0, stream>>>(zdbf, csr, offsets, sel, aggBF);
  k_gemm2<1, false, true><<<GEMM_GRID, 256, 0, stream>>>(aggBF, W_u1, nullptr, nullptr,
                                                         b_u1, bufB, score, sel, bufB,
                                                         zdbf);
  // diffusion 2: gather bf16(d), epilogue passthrough from f32 d
  k_agg_bf<false><<<GEMM_GRID * 0 + NN / 4, 256, 0, stream>>>(zdbf, csr, offsets, nullptr, aggBF);
  k_gemm2<2, false, true><<<GEMM_GRID, 256, 0, stream>>>(aggBF, W_u2, nullptr, nullptr,
                                                         b_u2, bufB, nullptr, sel, out,
                                                         nullptr);
}

// Round 5
// 899.436 us; speedup vs baseline: 1.1016x; 1.1016x over previous
//
#include <hip/hip_runtime.h>

#define NN 100000
#define NE 1600000
#define FF 128
#define KK 25000
#define NB ((NN + 255) / 256)   // 391 blocks of 256 over nodes
#define BM 128
#define BK 16
#define GEMM_GRID ((NN + BM - 1) / BM)

// ---------- bf16 helpers (packed pairs in a uint) ----------
__device__ __forceinline__ unsigned short f2b(float f) {
  unsigned u = __float_as_uint(f);
  u += 0x7FFFu + ((u >> 16) & 1u);  // round-to-nearest-even
  return (unsigned short)(u >> 16);
}
__device__ __forceinline__ unsigned pack2(float lo, float hi) {
  return (unsigned)f2b(lo) | ((unsigned)f2b(hi) << 16);
}

// ---------- top-k key ----------
__device__ __forceinline__ unsigned long long topk_key(float s, unsigned i) {
  // score is sigmoid output (>=0) so float bits are monotonic in value.
  return (((unsigned long long)__float_as_uint(s)) << 32) |
         (unsigned long long)(0xFFFFFFFFu - i);
}

// ---------- CSR build ----------
__global__ __launch_bounds__(256) void k_degree(const int* __restrict__ tgt,
                                                int* __restrict__ cnt) {
  int e = blockIdx.x * 256 + threadIdx.x;
  if (e < NE) atomicAdd(&cnt[tgt[e]], 1);
}

__global__ __launch_bounds__(256) void k_blocksum(const int* __restrict__ cnt,
                                                  int* __restrict__ bsum) {
  __shared__ int s[256];
  int i = blockIdx.x * 256 + threadIdx.x;
  s[threadIdx.x] = (i < NN) ? cnt[i] : 0;
  __syncthreads();
  for (int off = 128; off > 0; off >>= 1) {
    if (threadIdx.x < off) s[threadIdx.x] += s[threadIdx.x + off];
    __syncthreads();
  }
  if (threadIdx.x == 0) bsum[blockIdx.x] = s[0];
}

__global__ __launch_bounds__(512) void k_scan_bsum(int* __restrict__ bsum) {
  __shared__ int s[512];
  int t = threadIdx.x;
  int own = (t < NB) ? bsum[t] : 0;
  s[t] = own;
  __syncthreads();
  for (int off = 1; off < 512; off <<= 1) {
    int v = (t >= off) ? s[t - off] : 0;
    __syncthreads();
    s[t] += v;
    __syncthreads();
  }
  if (t < NB) bsum[t] = s[t] - own;  // exclusive
}

__global__ __launch_bounds__(256) void k_scan_final(const int* __restrict__ cnt,
                                                    const int* __restrict__ bsum,
                                                    int* __restrict__ offsets) {
  __shared__ int s[256];
  int i = blockIdx.x * 256 + threadIdx.x;
  int own = (i < NN) ? cnt[i] : 0;
  s[threadIdx.x] = own;
  __syncthreads();
  for (int off = 1; off < 256; off <<= 1) {
    int v = (threadIdx.x >= off) ? s[threadIdx.x - off] : 0;
    __syncthreads();
    s[threadIdx.x] += v;
    __syncthreads();
  }
  if (i < NN) offsets[i] = bsum[blockIdx.x] + s[threadIdx.x] - own;
  if (i == NN - 1) offsets[NN] = bsum[blockIdx.x] + s[threadIdx.x];
}

__global__ __launch_bounds__(256) void k_fill(const int* __restrict__ src,
                                              const int* __restrict__ tgt,
                                              const int* __restrict__ offsets,
                                              int* __restrict__ cursor,
                                              int* __restrict__ csr_src) {
  int e = blockIdx.x * 256 + threadIdx.x;
  if (e < NE) {
    int t = tgt[e];
    int p = atomicAdd(&cursor[t], 1);
    csr_src[offsets[t] + p] = src[e];
  }
}

// ---------- f32 mean aggregation (1 wave per node), order-preserving unroll x4 ----------
__global__ __launch_bounds__(256) void k_agg(const float* __restrict__ vals,
                                             const int* __restrict__ csr,
                                             const int* __restrict__ offsets,
                                             float* __restrict__ outv) {
  int w = threadIdx.x >> 6;
  int lane = threadIdx.x & 63;
  int node = blockIdx.x * 4 + w;
  if (node >= NN) return;
  int beg = offsets[node];
  int end = offsets[node + 1];
  float ax = 0.f, ay = 0.f;
  int e = beg;
  int e4 = beg + ((end - beg) & ~3);
  for (; e < e4; e += 4) {
    int j0 = csr[e], j1 = csr[e + 1], j2 = csr[e + 2], j3 = csr[e + 3];
    float2 v0 = *reinterpret_cast<const float2*>(&vals[(size_t)j0 * FF + lane * 2]);
    float2 v1 = *reinterpret_cast<const float2*>(&vals[(size_t)j1 * FF + lane * 2]);
    float2 v2 = *reinterpret_cast<const float2*>(&vals[(size_t)j2 * FF + lane * 2]);
    float2 v3 = *reinterpret_cast<const float2*>(&vals[(size_t)j3 * FF + lane * 2]);
    ax += v0.x; ay += v0.y;
    ax += v1.x; ay += v1.y;
    ax += v2.x; ay += v2.y;
    ax += v3.x; ay += v3.y;
  }
  for (; e < end; ++e) {
    int j = csr[e];
    float2 v = *reinterpret_cast<const float2*>(&vals[(size_t)j * FF + lane * 2]);
    ax += v.x; ay += v.y;
  }
  int deg = end - beg;
  float inv = 1.0f / (float)(deg > 0 ? deg : 1);
  float2 o;
  o.x = ax * inv;
  o.y = ay * inv;
  *reinterpret_cast<float2*>(&outv[(size_t)node * FF + lane * 2]) = o;
}

// ---------- bf16 mean aggregation (1 wave per node), order-preserving unroll x4 ----------
template <bool GATED>
__global__ __launch_bounds__(256) void k_agg_bf(const unsigned* __restrict__ vals,
                                                const int* __restrict__ csr,
                                                const int* __restrict__ offsets,
                                                const float* __restrict__ sel,
                                                unsigned* __restrict__ outv) {
  int w = threadIdx.x >> 6;
  int lane = threadIdx.x & 63;
  int node = blockIdx.x * 4 + w;
  if (node >= NN) return;
  int beg = offsets[node];
  int end = offsets[node + 1];
  float ax = 0.f, ay = 0.f;
  int e = beg;
  int e4 = beg + ((end - beg) & ~3);
  for (; e < e4; e += 4) {
    int j0 = csr[e], j1 = csr[e + 1], j2 = csr[e + 2], j3 = csr[e + 3];
    unsigned u0 = (!GATED || sel[j0] != 0.f) ? vals[(size_t)j0 * (FF / 2) + lane] : 0u;
    unsigned u1 = (!GATED || sel[j1] != 0.f) ? vals[(size_t)j1 * (FF / 2) + lane] : 0u;
    unsigned u2 = (!GATED || sel[j2] != 0.f) ? vals[(size_t)j2 * (FF / 2) + lane] : 0u;
    unsigned u3 = (!GATED || sel[j3] != 0.f) ? vals[(size_t)j3 * (FF / 2) + lane] : 0u;
    ax += __uint_as_float(u0 << 16); ay += __uint_as_float(u0 & 0xFFFF0000u);
    ax += __uint_as_float(u1 << 16); ay += __uint_as_float(u1 & 0xFFFF0000u);
    ax += __uint_as_float(u2 << 16); ay += __uint_as_float(u2 & 0xFFFF0000u);
    ax += __uint_as_float(u3 << 16); ay += __uint_as_float(u3 & 0xFFFF0000u);
  }
  for (; e < end; ++e) {
    int j = csr[e];
    unsigned u = (!GATED || sel[j] != 0.f) ? vals[(size_t)j * (FF / 2) + lane] : 0u;
    ax += __uint_as_float(u << 16); ay += __uint_as_float(u & 0xFFFF0000u);
  }
  int deg = end - beg;
  float inv = 1.0f / (float)(deg > 0 ? deg : 1);
  outv[(size_t)node * (FF / 2) + lane] = pack2(ax * inv, ay * inv);
}

// ---------- classic tiled SGEMM: [NN,128] x [128,128] f32 ----------
// BM=128, BN=128, BK=16, 256 threads, thread tile 8x8.
// tx = tid&15 (cols: tx*4..+4 and tx*4+64..+4), ty = tid>>4 (rows ty*8..+8).
// LDS: As[16][132] transposed (k-major, pad 4), Ws[16][128] natural layout. 16.6 KB.
// DUAL: second K-pass over (A2,W2) accumulates into the same registers.
// EPI 0: out = A@W (+ A2@W2) + bias
// EPI 1: g = A@W + bias; v = sel ? aux*score : g; out = relu(v); obf = packed bf16(out)
// EPI 2: g = A@W + bias; out = sel ? aux : g
template <int EPI, bool DUAL, bool ABF16>
__global__ __launch_bounds__(256, 4) void k_gemm3(const void* __restrict__ Araw,
                                                  const float* __restrict__ W,
                                                  const float* __restrict__ A2,
                                                  const float* __restrict__ W2,
                                                  const float* __restrict__ bias,
                                                  const float* __restrict__ aux,
                                                  const float* __restrict__ score,
                                                  const float* __restrict__ sel,
                                                  float* __restrict__ outv,
                                                  unsigned* __restrict__ obf) {
  __shared__ float As[BK][BM + 4];
  __shared__ float Ws[BK][FF];
  const int tid = threadIdx.x;
  const int tx = tid & 15;
  const int ty = tid >> 4;
  const int m0 = blockIdx.x * BM;

  float acc[8][8];
#pragma unroll
  for (int r = 0; r < 8; ++r)
#pragma unroll
    for (int j = 0; j < 8; ++j) acc[r][j] = 0.f;

  auto stage_a_f32 = [&](const float* Ag, int kt) {
#pragma unroll
    for (int t = 0; t < 2; ++t) {
      int i = tid + t * 256;      // 0..511
      int row = i >> 2;           // 0..127
      int c4 = i & 3;             // 0..3
      int gr = m0 + row;
      float4 v = make_float4(0.f, 0.f, 0.f, 0.f);
      if (gr < NN) v = *(const float4*)&Ag[(size_t)gr * FF + kt + c4 * 4];
      As[c4 * 4 + 0][row] = v.x;
      As[c4 * 4 + 1][row] = v.y;
      As[c4 * 4 + 2][row] = v.z;
      As[c4 * 4 + 3][row] = v.w;
    }
  };
  auto stage_a_bf = [&](const unsigned* Ab, int kt) {
#pragma unroll
    for (int t = 0; t < 4; ++t) {
      int i = tid + t * 256;      // 0..1023
      int row = i >> 3;           // 0..127
      int cu = i & 7;             // 0..7 -> local k = cu*2
      int gr = m0 + row;
      unsigned u = (gr < NN) ? Ab[(size_t)gr * (FF / 2) + (kt >> 1) + cu] : 0u;
      As[cu * 2 + 0][row] = __uint_as_float(u << 16);
      As[cu * 2 + 1][row] = __uint_as_float(u & 0xFFFF0000u);
    }
  };
  auto stage_w = [&](const float* Wg, int kt) {
#pragma unroll
    for (int t = 0; t < 2; ++t) {
      int i = tid + t * 256;      // 0..511
      int kr = i >> 5;            // 0..15
      int c4 = i & 31;
      float4 v = *(const float4*)&Wg[(size_t)(kt + kr) * FF + c4 * 4];
      *(float4*)&Ws[kr][c4 * 4] = v;
    }
  };
  auto compute = [&]() {
#pragma unroll
    for (int k = 0; k < BK; ++k) {
      float4 a0 = *(const float4*)&As[k][ty * 8];
      float4 a1 = *(const float4*)&As[k][ty * 8 + 4];
      float4 w0 = *(const float4*)&Ws[k][tx * 4];
      float4 w1 = *(const float4*)&Ws[k][tx * 4 + 64];
      float av[8] = {a0.x, a0.y, a0.z, a0.w, a1.x, a1.y, a1.z, a1.w};
      float wv[8] = {w0.x, w0.y, w0.z, w0.w, w1.x, w1.y, w1.z, w1.w};
#pragma unroll
      for (int r = 0; r < 8; ++r)
#pragma unroll
        for (int j = 0; j < 8; ++j) acc[r][j] = fmaf(av[r], wv[j], acc[r][j]);
    }
  };

  for (int kt = 0; kt < FF; kt += BK) {
    __syncthreads();
    if constexpr (ABF16) stage_a_bf((const unsigned*)Araw, kt);
    else stage_a_f32((const float*)Araw, kt);
    stage_w(W, kt);
    __syncthreads();
    compute();
  }
  if constexpr (DUAL) {
    for (int kt = 0; kt < FF; kt += BK) {
      __syncthreads();
      stage_a_f32(A2, kt);
      stage_w(W2, kt);
      __syncthreads();
      compute();
    }
  }

  float4 b0 = *(const float4*)&bias[tx * 4];
  float4 b1 = *(const float4*)&bias[tx * 4 + 64];
  float bs[8] = {b0.x, b0.y, b0.z, b0.w, b1.x, b1.y, b1.z, b1.w};

#pragma unroll
  for (int r = 0; r < 8; ++r) {
    int gi = m0 + ty * 8 + r;
    if (gi >= NN) continue;
    size_t base = (size_t)gi * FF;
    float v[8];
    if (EPI == 0) {
#pragma unroll
      for (int j = 0; j < 8; ++j) v[j] = acc[r][j] + bs[j];
    } else if (EPI == 1) {
      float se = sel[gi];
      float sc = score[gi];
      float4 x0 = *(const float4*)&aux[base + tx * 4];
      float4 x1 = *(const float4*)&aux[base + tx * 4 + 64];
      float av[8] = {x0.x, x0.y, x0.z, x0.w, x1.x, x1.y, x1.z, x1.w};
#pragma unroll
      for (int j = 0; j < 8; ++j) {
        float g = acc[r][j] + bs[j];
        float t = (se != 0.f) ? av[j] * sc : g;
        v[j] = fmaxf(t, 0.f);
      }
      uint2 p0, p1;
      p0.x = pack2(v[0], v[1]);
      p0.y = pack2(v[2], v[3]);
      p1.x = pack2(v[4], v[5]);
      p1.y = pack2(v[6], v[7]);
      *(uint2*)&obf[(size_t)gi * (FF / 2) + tx * 2] = p0;
      *(uint2*)&obf[(size_t)gi * (FF / 2) + 32 + tx * 2] = p1;
    } else {
      float se = sel[gi];
      float4 x0 = *(const float4*)&aux[base + tx * 4];
      float4 x1 = *(const float4*)&aux[base + tx * 4 + 64];
      float av[8] = {x0.x, x0.y, x0.z, x0.w, x1.x, x1.y, x1.z, x1.w};
#pragma unroll
      for (int j = 0; j < 8; ++j) {
        float g = acc[r][j] + bs[j];
        v[j] = (se != 0.f) ? av[j] : g;
      }
    }
    *(float4*)&outv[base + tx * 4] = make_float4(v[0], v[1], v[2], v[3]);
    *(float4*)&outv[base + tx * 4 + 64] = make_float4(v[4], v[5], v[6], v[7]);
  }
}

// ---------- scorer ----------
__global__ __launch_bounds__(256) void k_score(const float* __restrict__ h,
                                               const float* __restrict__ wsc,
                                               const float* __restrict__ bsc,
                                               float* __restrict__ score) {
  int lane = threadIdx.x & 63;
  int w = threadIdx.x >> 6;
  int i = blockIdx.x * 4 + w;
  if (i >= NN) return;
  float2 a = *reinterpret_cast<const float2*>(&h[(size_t)i * FF + lane * 2]);
  float2 ww = *reinterpret_cast<const float2*>(&wsc[lane * 2]);
  float v = a.x * ww.x + a.y * ww.y;
#pragma unroll
  for (int off = 32; off > 0; off >>= 1) v += __shfl_xor(v, off, 64);
  if (lane == 0) {
    float t = v + bsc[0];
    score[i] = 1.0f / (1.0f + expf(-t));
  }
}

// ---------- exact top-K: 8-round radix select on 64-bit composite key ----------
__global__ void k_init_state(unsigned* state) {
  state[0] = 0u;  // prefix hi
  state[1] = 0u;  // prefix lo
  state[2] = KK;  // remaining rank
}

__global__ __launch_bounds__(256) void k_hist(const float* __restrict__ score,
                                              const unsigned* __restrict__ state,
                                              unsigned* __restrict__ hist,
                                              int bits_fixed) {
  __shared__ unsigned lh[256];
  for (int i = threadIdx.x; i < 256; i += 256) lh[i] = 0;
  __syncthreads();
  unsigned long long prefix =
      (((unsigned long long)state[0]) << 32) | (unsigned long long)state[1];
  int i = blockIdx.x * 256 + threadIdx.x;
  if (i < NN) {
    unsigned long long key = topk_key(score[i], (unsigned)i);
    bool ok = (bits_fixed == 0) ? true : (((key ^ prefix) >> (64 - bits_fixed)) == 0ull);
    if (ok) {
      unsigned b = (unsigned)((key >> (56 - bits_fixed)) & 0xFFull);
      atomicAdd(&lh[b], 1u);
    }
  }
  __syncthreads();
  for (int i2 = threadIdx.x; i2 < 256; i2 += 256)
    if (lh[i2]) atomicAdd(&hist[i2], lh[i2]);
}

__global__ __launch_bounds__(256) void k_select_round(unsigned* __restrict__ state,
                                                      unsigned* __restrict__ hist,
                                                      int bits_fixed) {
  __shared__ unsigned h[256];
  int t = threadIdx.x;
  h[t] = hist[t];
  hist[t] = 0;  // ready for next round
  __syncthreads();
  if (t == 0) {
    unsigned rem = state[2];
    unsigned long long prefix =
        (((unsigned long long)state[0]) << 32) | (unsigned long long)state[1];
    unsigned cum = 0;
    int bstar = 0;
    for (int b = 255; b >= 0; --b) {
      unsigned c = h[b];
      if (cum + c >= rem) { bstar = b; break; }
      cum += c;
    }
    rem -= cum;
    prefix |= ((unsigned long long)bstar) << (56 - bits_fixed);
    state[0] = (unsigned)(prefix >> 32);
    state[1] = (unsigned)(prefix & 0xFFFFFFFFull);
    state[2] = rem;
  }
}

__global__ __launch_bounds__(256) void k_mask(const float* __restrict__ score,
                                              const unsigned* __restrict__ state,
                                              float* __restrict__ sel) {
  int i = blockIdx.x * 256 + threadIdx.x;
  if (i >= NN) return;
  unsigned long long T =
      (((unsigned long long)state[0]) << 32) | (unsigned long long)state[1];
  unsigned long long key = topk_key(score[i], (unsigned)i);
  sel[i] = (key >= T) ? 1.0f : 0.0f;
}

// ---------- pack gated z rows (selected only) to bf16 ----------
__global__ __launch_bounds__(256) void k_gate_zg(const float* __restrict__ h,
                                                 const float* __restrict__ score,
                                                 const float* __restrict__ sel,
                                                 unsigned* __restrict__ zg) {
  int w = threadIdx.x >> 6;
  int lane = threadIdx.x & 63;
  int node = blockIdx.x * 4 + w;
  if (node >= NN) return;
  if (sel[node] == 0.f) return;
  float s = score[node];
  float2 v = *reinterpret_cast<const float2*>(&h[(size_t)node * FF + lane * 2]);
  zg[(size_t)node * (FF / 2) + lane] = pack2(v.x * s, v.y * s);
}

// ---------- launch ----------
extern "C" void kernel_launch(void* const* d_in, const int* in_sizes, int n_in,
                              void* d_out, int out_size, void* d_ws, size_t ws_size,
                              hipStream_t stream) {
  const float* x = (const float*)d_in[0];
  const int* src = (const int*)d_in[1];
  const int* tgt = (const int*)d_in[2];
  const float* W_self = (const float*)d_in[3];
  const float* W_neigh = (const float*)d_in[4];
  const float* b_pack = (const float*)d_in[5];
  const float* w_score = (const float*)d_in[6];
  const float* b_score = (const float*)d_in[7];
  const float* W_u1 = (const float*)d_in[8];
  const float* b_u1 = (const float*)d_in[9];
  const float* W_u2 = (const float*)d_in[10];
  const float* b_u2 = (const float*)d_in[11];
  float* out = (float*)d_out;

  char* ws = (char*)d_ws;
  size_t off = 0;
  auto alloc = [&](size_t bytes) -> char* {
    char* p = ws + off;
    off += (bytes + 255) & ~(size_t)255;
    return p;
  };
  int* cnt = (int*)alloc((size_t)NN * 4);
  int* offsets = (int*)alloc((size_t)(NN + 1) * 4);
  int* cursor = (int*)alloc((size_t)NN * 4);
  int* csr = (int*)alloc((size_t)NE * 4);
  float* score = (float*)alloc((size_t)NN * 4);
  float* sel = (float*)alloc((size_t)NN * 4);
  int* bsum = (int*)alloc(512 * 4);
  unsigned* hist = (unsigned*)alloc(256 * 4);
  unsigned* state = (unsigned*)alloc(64);
  float* aggF = (float*)alloc((size_t)NN * FF * 4);  // 51.2 MB, reused after gemm0:
  unsigned* zdbf = (unsigned*)aggF;                   //   first half: z-bf16 then d-bf16
  unsigned* aggBF = (unsigned*)(aggF + (size_t)NN * (FF / 2));  // second half: bf16 agg out
  float* bufB = out;  // h, then d, live in d_out (element-wise in-place safe)

  hipMemsetAsync(cnt, 0, (size_t)NN * 4, stream);
  hipMemsetAsync(cursor, 0, (size_t)NN * 4, stream);
  hipMemsetAsync(hist, 0, 256 * 4, stream);
  k_init_state<<<1, 1, 0, stream>>>(state);

  // CSR by target
  k_degree<<<(NE + 255) / 256, 256, 0, stream>>>(tgt, cnt);
  k_blocksum<<<NB, 256, 0, stream>>>(cnt, bsum);
  k_scan_bsum<<<1, 512, 0, stream>>>(bsum);
  k_scan_final<<<NB, 256, 0, stream>>>(cnt, bsum, offsets);
  k_fill<<<(NE + 255) / 256, 256, 0, stream>>>(src, tgt, offsets, cursor, csr);

  // ---- compress (all f32: score path is selection-critical) ----
  k_agg<<<NN / 4, 256, 0, stream>>>(x, csr, offsets, aggF);
  k_gemm3<0, true, false><<<GEMM_GRID, 256, 0, stream>>>(aggF, W_neigh, x, W_self,
                                                         b_pack, nullptr, nullptr,
                                                         nullptr, bufB, nullptr);
  k_score<<<NN / 4, 256, 0, stream>>>(bufB, w_score, b_score, score);

  // exact top-K (radix select, no host sync)
  for (int r = 0; r < 8; ++r) {
    k_hist<<<NB, 256, 0, stream>>>(score, state, hist, 8 * r);
    k_select_round<<<1, 256, 0, stream>>>(state, hist, 8 * r);
  }
  k_mask<<<NB, 256, 0, stream>>>(score, state, sel);

  // ---- decompress (bf16 gathers; selected rows stay f32) ----
  // diffusion 1: zg rows written only where selected; gated agg skips others
  k_gate_zg<<<NN / 4, 256, 0, stream>>>(bufB, score, sel, zdbf);
  k_agg_bf<true><<<NN / 4, 256, 0, stream>>>(zdbf, csr, offsets, sel, aggBF);
  k_gemm3<1, false, true><<<GEMM_GRID, 256, 0, stream>>>(aggBF, W_u1, nullptr, nullptr,
                                                         b_u1, bufB, score, sel, bufB,
                                                         zdbf);
  // diffusion 2: gather bf16(d), epilogue passthrough from f32 d
  k_agg_bf<false><<<NN / 4, 256, 0, stream>>>(zdbf, csr, offsets, nullptr, aggBF);
  k_gemm3<2, false, true><<<GEMM_GRID, 256, 0, stream>>>(aggBF, W_u2, nullptr, nullptr,
                                                         b_u2, bufB, nullptr, sel, out,
                                                         nullptr);
}

// Round 6
// 765.878 us; speedup vs baseline: 1.2937x; 1.1744x over previous
//
#include <hip/hip_runtime.h>

#define NN 100000
#define NE 1600000
#define FF 128
#define KK 25000
#define NB ((NN + 255) / 256)   // 391 blocks of 256 over nodes
#define BM 64
#define BK 32
#define GEMM_GRID ((NN + BM - 1) / BM)

// ---------- bf16 helpers (packed pairs in a uint) ----------
__device__ __forceinline__ unsigned short f2b(float f) {
  unsigned u = __float_as_uint(f);
  u += 0x7FFFu + ((u >> 16) & 1u);  // round-to-nearest-even
  return (unsigned short)(u >> 16);
}
__device__ __forceinline__ unsigned pack2(float lo, float hi) {
  return (unsigned)f2b(lo) | ((unsigned)f2b(hi) << 16);
}

// ---------- top-k key ----------
__device__ __forceinline__ unsigned long long topk_key(float s, unsigned i) {
  // score is sigmoid output (>=0) so float bits are monotonic in value.
  return (((unsigned long long)__float_as_uint(s)) << 32) |
         (unsigned long long)(0xFFFFFFFFu - i);
}

// ---------- CSR build ----------
__global__ __launch_bounds__(256) void k_degree(const int* __restrict__ tgt,
                                                int* __restrict__ cnt) {
  int e = blockIdx.x * 256 + threadIdx.x;
  if (e < NE) atomicAdd(&cnt[tgt[e]], 1);
}

__global__ __launch_bounds__(256) void k_blocksum(const int* __restrict__ cnt,
                                                  int* __restrict__ bsum) {
  __shared__ int s[256];
  int i = blockIdx.x * 256 + threadIdx.x;
  s[threadIdx.x] = (i < NN) ? cnt[i] : 0;
  __syncthreads();
  for (int off = 128; off > 0; off >>= 1) {
    if (threadIdx.x < off) s[threadIdx.x] += s[threadIdx.x + off];
    __syncthreads();
  }
  if (threadIdx.x == 0) bsum[blockIdx.x] = s[0];
}

__global__ __launch_bounds__(512) void k_scan_bsum(int* __restrict__ bsum) {
  __shared__ int s[512];
  int t = threadIdx.x;
  int own = (t < NB) ? bsum[t] : 0;
  s[t] = own;
  __syncthreads();
  for (int off = 1; off < 512; off <<= 1) {
    int v = (t >= off) ? s[t - off] : 0;
    __syncthreads();
    s[t] += v;
    __syncthreads();
  }
  if (t < NB) bsum[t] = s[t] - own;  // exclusive
}

__global__ __launch_bounds__(256) void k_scan_final(const int* __restrict__ cnt,
                                                    const int* __restrict__ bsum,
                                                    int* __restrict__ offsets) {
  __shared__ int s[256];
  int i = blockIdx.x * 256 + threadIdx.x;
  int own = (i < NN) ? cnt[i] : 0;
  s[threadIdx.x] = own;
  __syncthreads();
  for (int off = 1; off < 256; off <<= 1) {
    int v = (threadIdx.x >= off) ? s[threadIdx.x - off] : 0;
    __syncthreads();
    s[threadIdx.x] += v;
    __syncthreads();
  }
  if (i < NN) offsets[i] = bsum[blockIdx.x] + s[threadIdx.x] - own;
  if (i == NN - 1) offsets[NN] = bsum[blockIdx.x] + s[threadIdx.x];
}

__global__ __launch_bounds__(256) void k_fill(const int* __restrict__ src,
                                              const int* __restrict__ tgt,
                                              const int* __restrict__ offsets,
                                              int* __restrict__ cursor,
                                              int* __restrict__ csr_src) {
  int e = blockIdx.x * 256 + threadIdx.x;
  if (e < NE) {
    int t = tgt[e];
    int p = atomicAdd(&cursor[t], 1);
    csr_src[offsets[t] + p] = src[e];
  }
}

// ---------- f32 mean aggregation (1 wave per node), order-preserving unroll x4 ----------
__global__ __launch_bounds__(256) void k_agg(const float* __restrict__ vals,
                                             const int* __restrict__ csr,
                                             const int* __restrict__ offsets,
                                             float* __restrict__ outv) {
  int w = threadIdx.x >> 6;
  int lane = threadIdx.x & 63;
  int node = blockIdx.x * 4 + w;
  if (node >= NN) return;
  int beg = offsets[node];
  int end = offsets[node + 1];
  float ax = 0.f, ay = 0.f;
  int e = beg;
  int e4 = beg + ((end - beg) & ~3);
  for (; e < e4; e += 4) {
    int j0 = csr[e], j1 = csr[e + 1], j2 = csr[e + 2], j3 = csr[e + 3];
    float2 v0 = *reinterpret_cast<const float2*>(&vals[(size_t)j0 * FF + lane * 2]);
    float2 v1 = *reinterpret_cast<const float2*>(&vals[(size_t)j1 * FF + lane * 2]);
    float2 v2 = *reinterpret_cast<const float2*>(&vals[(size_t)j2 * FF + lane * 2]);
    float2 v3 = *reinterpret_cast<const float2*>(&vals[(size_t)j3 * FF + lane * 2]);
    ax += v0.x; ay += v0.y;
    ax += v1.x; ay += v1.y;
    ax += v2.x; ay += v2.y;
    ax += v3.x; ay += v3.y;
  }
  for (; e < end; ++e) {
    int j = csr[e];
    float2 v = *reinterpret_cast<const float2*>(&vals[(size_t)j * FF + lane * 2]);
    ax += v.x; ay += v.y;
  }
  int deg = end - beg;
  float inv = 1.0f / (float)(deg > 0 ? deg : 1);
  float2 o;
  o.x = ax * inv;
  o.y = ay * inv;
  *reinterpret_cast<float2*>(&outv[(size_t)node * FF + lane * 2]) = o;
}

// ---------- bf16 mean aggregation (1 wave per node), order-preserving unroll x4 ----------
template <bool GATED>
__global__ __launch_bounds__(256) void k_agg_bf(const unsigned* __restrict__ vals,
                                                const int* __restrict__ csr,
                                                const int* __restrict__ offsets,
                                                const float* __restrict__ sel,
                                                unsigned* __restrict__ outv) {
  int w = threadIdx.x >> 6;
  int lane = threadIdx.x & 63;
  int node = blockIdx.x * 4 + w;
  if (node >= NN) return;
  int beg = offsets[node];
  int end = offsets[node + 1];
  float ax = 0.f, ay = 0.f;
  int e = beg;
  int e4 = beg + ((end - beg) & ~3);
  for (; e < e4; e += 4) {
    int j0 = csr[e], j1 = csr[e + 1], j2 = csr[e + 2], j3 = csr[e + 3];
    unsigned u0 = (!GATED || sel[j0] != 0.f) ? vals[(size_t)j0 * (FF / 2) + lane] : 0u;
    unsigned u1 = (!GATED || sel[j1] != 0.f) ? vals[(size_t)j1 * (FF / 2) + lane] : 0u;
    unsigned u2 = (!GATED || sel[j2] != 0.f) ? vals[(size_t)j2 * (FF / 2) + lane] : 0u;
    unsigned u3 = (!GATED || sel[j3] != 0.f) ? vals[(size_t)j3 * (FF / 2) + lane] : 0u;
    ax += __uint_as_float(u0 << 16); ay += __uint_as_float(u0 & 0xFFFF0000u);
    ax += __uint_as_float(u1 << 16); ay += __uint_as_float(u1 & 0xFFFF0000u);
    ax += __uint_as_float(u2 << 16); ay += __uint_as_float(u2 & 0xFFFF0000u);
    ax += __uint_as_float(u3 << 16); ay += __uint_as_float(u3 & 0xFFFF0000u);
  }
  for (; e < end; ++e) {
    int j = csr[e];
    unsigned u = (!GATED || sel[j] != 0.f) ? vals[(size_t)j * (FF / 2) + lane] : 0u;
    ax += __uint_as_float(u << 16); ay += __uint_as_float(u & 0xFFFF0000u);
  }
  int deg = end - beg;
  float inv = 1.0f / (float)(deg > 0 ? deg : 1);
  outv[(size_t)node * (FF / 2) + lane] = pack2(ax * inv, ay * inv);
}

// ---------- tiled SGEMM: [NN,128] x [128,128] f32 ----------
// BM=64, BN=128, BK=32, 256 threads, thread tile 4x8 (32 acc -> no spill risk).
// tx = tid&15 (cols tx*4..+4 and tx*4+64..+4), ty = tid>>4 (rows ty*4..+4).
// LDS: As[32][68] transposed (pad 4, 16B-aligned rows), Ws[32][128]. 24.5 KB.
// DUAL: second K-pass over (A2,W2) accumulates into the same registers.
// EPI 0: out = A@W (+ A2@W2) + bias
// EPI 1: g = A@W + bias; v = sel ? aux*score : g; out = relu(v); obf = packed bf16(out)
// EPI 2: g = A@W + bias; out = sel ? aux : g
template <int EPI, bool DUAL, bool ABF16>
__global__ __launch_bounds__(256) void k_gemm4(const void* __restrict__ Araw,
                                               const float* __restrict__ W,
                                               const float* __restrict__ A2,
                                               const float* __restrict__ W2,
                                               const float* __restrict__ bias,
                                               const float* __restrict__ aux,
                                               const float* __restrict__ score,
                                               const float* __restrict__ sel,
                                               float* __restrict__ outv,
                                               unsigned* __restrict__ obf) {
  __shared__ float As[BK][BM + 4];
  __shared__ float Ws[BK][FF];
  const int tid = threadIdx.x;
  const int tx = tid & 15;
  const int ty = tid >> 4;
  const int m0 = blockIdx.x * BM;

  float acc[4][8];
#pragma unroll
  for (int r = 0; r < 4; ++r)
#pragma unroll
    for (int j = 0; j < 8; ++j) acc[r][j] = 0.f;

  const int NPASS = DUAL ? 2 : 1;
  for (int pass = 0; pass < NPASS; ++pass) {
    const float* Wp = (pass == 0) ? W : W2;
    for (int kt = 0; kt < FF; kt += BK) {
      __syncthreads();
      // ---- stage A (transposed into As[k][row]) ----
      if (pass == 0 && ABF16) {
        const unsigned* Ab = (const unsigned*)Araw;
#pragma unroll
        for (int t = 0; t < 4; ++t) {
          int i = tid + t * 256;      // 0..1023
          int row = i >> 4;           // 0..63
          int cu = i & 15;            // 0..15 -> local k = cu*2
          int gr = m0 + row;
          unsigned u = (gr < NN) ? Ab[(size_t)gr * (FF / 2) + (kt >> 1) + cu] : 0u;
          As[cu * 2 + 0][row] = __uint_as_float(u << 16);
          As[cu * 2 + 1][row] = __uint_as_float(u & 0xFFFF0000u);
        }
      } else {
        const float* Ag = (pass == 0) ? (const float*)Araw : A2;
#pragma unroll
        for (int t = 0; t < 2; ++t) {
          int i = tid + t * 256;      // 0..511
          int row = i >> 3;           // 0..63
          int c8 = i & 7;             // 0..7 -> local k = c8*4
          int gr = m0 + row;
          float4 v = make_float4(0.f, 0.f, 0.f, 0.f);
          if (gr < NN) v = *(const float4*)&Ag[(size_t)gr * FF + kt + c8 * 4];
          As[c8 * 4 + 0][row] = v.x;
          As[c8 * 4 + 1][row] = v.y;
          As[c8 * 4 + 2][row] = v.z;
          As[c8 * 4 + 3][row] = v.w;
        }
      }
      // ---- stage W ----
#pragma unroll
      for (int t = 0; t < 4; ++t) {
        int i = tid + t * 256;        // 0..1023
        int kr = i >> 5;              // 0..31
        int c4 = i & 31;
        *(float4*)&Ws[kr][c4 * 4] =
            *(const float4*)&Wp[(size_t)(kt + kr) * FF + c4 * 4];
      }
      __syncthreads();
      // ---- compute ----
#pragma unroll
      for (int k = 0; k < BK; ++k) {
        float4 a = *(const float4*)&As[k][ty * 4];
        float4 w0 = *(const float4*)&Ws[k][tx * 4];
        float4 w1 = *(const float4*)&Ws[k][tx * 4 + 64];
        float av[4] = {a.x, a.y, a.z, a.w};
        float wv[8] = {w0.x, w0.y, w0.z, w0.w, w1.x, w1.y, w1.z, w1.w};
#pragma unroll
        for (int r = 0; r < 4; ++r)
#pragma unroll
          for (int j = 0; j < 8; ++j) acc[r][j] = fmaf(av[r], wv[j], acc[r][j]);
      }
    }
  }

  float4 b0 = *(const float4*)&bias[tx * 4];
  float4 b1 = *(const float4*)&bias[tx * 4 + 64];
  float bs[8] = {b0.x, b0.y, b0.z, b0.w, b1.x, b1.y, b1.z, b1.w};

#pragma unroll
  for (int r = 0; r < 4; ++r) {
    int gi = m0 + ty * 4 + r;
    if (gi >= NN) continue;
    size_t base = (size_t)gi * FF;
    float v[8];
    if (EPI == 0) {
#pragma unroll
      for (int j = 0; j < 8; ++j) v[j] = acc[r][j] + bs[j];
    } else if (EPI == 1) {
      float se = sel[gi];
      float sc = score[gi];
      float4 x0 = *(const float4*)&aux[base + tx * 4];
      float4 x1 = *(const float4*)&aux[base + tx * 4 + 64];
      float av[8] = {x0.x, x0.y, x0.z, x0.w, x1.x, x1.y, x1.z, x1.w};
#pragma unroll
      for (int j = 0; j < 8; ++j) {
        float g = acc[r][j] + bs[j];
        float t = (se != 0.f) ? av[j] * sc : g;
        v[j] = fmaxf(t, 0.f);
      }
      uint2 p0, p1;
      p0.x = pack2(v[0], v[1]);
      p0.y = pack2(v[2], v[3]);
      p1.x = pack2(v[4], v[5]);
      p1.y = pack2(v[6], v[7]);
      *(uint2*)&obf[(size_t)gi * (FF / 2) + tx * 2] = p0;
      *(uint2*)&obf[(size_t)gi * (FF / 2) + 32 + tx * 2] = p1;
    } else {
      float se = sel[gi];
      float4 x0 = *(const float4*)&aux[base + tx * 4];
      float4 x1 = *(const float4*)&aux[base + tx * 4 + 64];
      float av[8] = {x0.x, x0.y, x0.z, x0.w, x1.x, x1.y, x1.z, x1.w};
#pragma unroll
      for (int j = 0; j < 8; ++j) {
        float g = acc[r][j] + bs[j];
        v[j] = (se != 0.f) ? av[j] : g;
      }
    }
    *(float4*)&outv[base + tx * 4] = make_float4(v[0], v[1], v[2], v[3]);
    *(float4*)&outv[base + tx * 4 + 64] = make_float4(v[4], v[5], v[6], v[7]);
  }
}

// ---------- scorer ----------
__global__ __launch_bounds__(256) void k_score(const float* __restrict__ h,
                                               const float* __restrict__ wsc,
                                               const float* __restrict__ bsc,
                                               float* __restrict__ score) {
  int lane = threadIdx.x & 63;
  int w = threadIdx.x >> 6;
  int i = blockIdx.x * 4 + w;
  if (i >= NN) return;
  float2 a = *reinterpret_cast<const float2*>(&h[(size_t)i * FF + lane * 2]);
  float2 ww = *reinterpret_cast<const float2*>(&wsc[lane * 2]);
  float v = a.x * ww.x + a.y * ww.y;
#pragma unroll
  for (int off = 32; off > 0; off >>= 1) v += __shfl_xor(v, off, 64);
  if (lane == 0) {
    float t = v + bsc[0];
    score[i] = 1.0f / (1.0f + expf(-t));
  }
}

// ---------- exact top-K: 8-round radix select on 64-bit composite key ----------
__global__ void k_init_state(unsigned* state) {
  state[0] = 0u;  // prefix hi
  state[1] = 0u;  // prefix lo
  state[2] = KK;  // remaining rank
}

__global__ __launch_bounds__(256) void k_hist(const float* __restrict__ score,
                                              const unsigned* __restrict__ state,
                                              unsigned* __restrict__ hist,
                                              int bits_fixed) {
  __shared__ unsigned lh[256];
  for (int i = threadIdx.x; i < 256; i += 256) lh[i] = 0;
  __syncthreads();
  unsigned long long prefix =
      (((unsigned long long)state[0]) << 32) | (unsigned long long)state[1];
  int i = blockIdx.x * 256 + threadIdx.x;
  if (i < NN) {
    unsigned long long key = topk_key(score[i], (unsigned)i);
    bool ok = (bits_fixed == 0) ? true : (((key ^ prefix) >> (64 - bits_fixed)) == 0ull);
    if (ok) {
      unsigned b = (unsigned)((key >> (56 - bits_fixed)) & 0xFFull);
      atomicAdd(&lh[b], 1u);
    }
  }
  __syncthreads();
  for (int i2 = threadIdx.x; i2 < 256; i2 += 256)
    if (lh[i2]) atomicAdd(&hist[i2], lh[i2]);
}

__global__ __launch_bounds__(256) void k_select_round(unsigned* __restrict__ state,
                                                      unsigned* __restrict__ hist,
                                                      int bits_fixed) {
  __shared__ unsigned h[256];
  int t = threadIdx.x;
  h[t] = hist[t];
  hist[t] = 0;  // ready for next round
  __syncthreads();
  if (t == 0) {
    unsigned rem = state[2];
    unsigned long long prefix =
        (((unsigned long long)state[0]) << 32) | (unsigned long long)state[1];
    unsigned cum = 0;
    int bstar = 0;
    for (int b = 255; b >= 0; --b) {
      unsigned c = h[b];
      if (cum + c >= rem) { bstar = b; break; }
      cum += c;
    }
    rem -= cum;
    prefix |= ((unsigned long long)bstar) << (56 - bits_fixed);
    state[0] = (unsigned)(prefix >> 32);
    state[1] = (unsigned)(prefix & 0xFFFFFFFFull);
    state[2] = rem;
  }
}

__global__ __launch_bounds__(256) void k_mask(const float* __restrict__ score,
                                              const unsigned* __restrict__ state,
                                              float* __restrict__ sel) {
  int i = blockIdx.x * 256 + threadIdx.x;
  if (i >= NN) return;
  unsigned long long T =
      (((unsigned long long)state[0]) << 32) | (unsigned long long)state[1];
  unsigned long long key = topk_key(score[i], (unsigned)i);
  sel[i] = (key >= T) ? 1.0f : 0.0f;
}

// ---------- pack gated z rows (selected only) to bf16 ----------
__global__ __launch_bounds__(256) void k_gate_zg(const float* __restrict__ h,
                                                 const float* __restrict__ score,
                                                 const float* __restrict__ sel,
                                                 unsigned* __restrict__ zg) {
  int w = threadIdx.x >> 6;
  int lane = threadIdx.x & 63;
  int node = blockIdx.x * 4 + w;
  if (node >= NN) return;
  if (sel[node] == 0.f) return;
  float s = score[node];
  float2 v = *reinterpret_cast<const float2*>(&h[(size_t)node * FF + lane * 2]);
  zg[(size_t)node * (FF / 2) + lane] = pack2(v.x * s, v.y * s);
}

// ---------- launch ----------
extern "C" void kernel_launch(void* const* d_in, const int* in_sizes, int n_in,
                              void* d_out, int out_size, void* d_ws, size_t ws_size,
                              hipStream_t stream) {
  const float* x = (const float*)d_in[0];
  const int* src = (const int*)d_in[1];
  const int* tgt = (const int*)d_in[2];
  const float* W_self = (const float*)d_in[3];
  const float* W_neigh = (const float*)d_in[4];
  const float* b_pack = (const float*)d_in[5];
  const float* w_score = (const float*)d_in[6];
  const float* b_score = (const float*)d_in[7];
  const float* W_u1 = (const float*)d_in[8];
  const float* b_u1 = (const float*)d_in[9];
  const float* W_u2 = (const float*)d_in[10];
  const float* b_u2 = (const float*)d_in[11];
  float* out = (float*)d_out;

  char* ws = (char*)d_ws;
  size_t off = 0;
  auto alloc = [&](size_t bytes) -> char* {
    char* p = ws + off;
    off += (bytes + 255) & ~(size_t)255;
    return p;
  };
  int* cnt = (int*)alloc((size_t)NN * 4);
  int* offsets = (int*)alloc((size_t)(NN + 1) * 4);
  int* cursor = (int*)alloc((size_t)NN * 4);
  int* csr = (int*)alloc((size_t)NE * 4);
  float* score = (float*)alloc((size_t)NN * 4);
  float* sel = (float*)alloc((size_t)NN * 4);
  int* bsum = (int*)alloc(512 * 4);
  unsigned* hist = (unsigned*)alloc(256 * 4);
  unsigned* state = (unsigned*)alloc(64);
  float* aggF = (float*)alloc((size_t)NN * FF * 4);  // 51.2 MB, reused after gemm0:
  unsigned* zdbf = (unsigned*)aggF;                   //   first half: z-bf16 then d-bf16
  unsigned* aggBF = (unsigned*)(aggF + (size_t)NN * (FF / 2));  // second half: bf16 agg out
  float* bufB = out;  // h, then d, live in d_out (element-wise in-place safe)

  hipMemsetAsync(cnt, 0, (size_t)NN * 4, stream);
  hipMemsetAsync(cursor, 0, (size_t)NN * 4, stream);
  hipMemsetAsync(hist, 0, 256 * 4, stream);
  k_init_state<<<1, 1, 0, stream>>>(state);

  // CSR by target
  k_degree<<<(NE + 255) / 256, 256, 0, stream>>>(tgt, cnt);
  k_blocksum<<<NB, 256, 0, stream>>>(cnt, bsum);
  k_scan_bsum<<<1, 512, 0, stream>>>(bsum);
  k_scan_final<<<NB, 256, 0, stream>>>(cnt, bsum, offsets);
  k_fill<<<(NE + 255) / 256, 256, 0, stream>>>(src, tgt, offsets, cursor, csr);

  // ---- compress (all f32: score path is selection-critical) ----
  k_agg<<<NN / 4, 256, 0, stream>>>(x, csr, offsets, aggF);
  k_gemm4<0, true, false><<<GEMM_GRID, 256, 0, stream>>>(aggF, W_neigh, x, W_self,
                                                         b_pack, nullptr, nullptr,
                                                         nullptr, bufB, nullptr);
  k_score<<<NN / 4, 256, 0, stream>>>(bufB, w_score, b_score, score);

  // exact top-K (radix select, no host sync)
  for (int r = 0; r < 8; ++r) {
    k_hist<<<NB, 256, 0, stream>>>(score, state, hist, 8 * r);
    k_select_round<<<1, 256, 0, stream>>>(state, hist, 8 * r);
  }
  k_mask<<<NB, 256, 0, stream>>>(score, state, sel);

  // ---- decompress (bf16 gathers; selected rows stay f32) ----
  // diffusion 1: zg rows written only where selected; gated agg skips others
  k_gate_zg<<<NN / 4, 256, 0, stream>>>(bufB, score, sel, zdbf);
  k_agg_bf<true><<<NN / 4, 256, 0, stream>>>(zdbf, csr, offsets, sel, aggBF);
  k_gemm4<1, false, true><<<GEMM_GRID, 256, 0, stream>>>(aggBF, W_u1, nullptr, nullptr,
                                                         b_u1, bufB, score, sel, bufB,
                                                         zdbf);
  // diffusion 2: gather bf16(d), epilogue passthrough from f32 d
  k_agg_bf<false><<<NN / 4, 256, 0, stream>>>(zdbf, csr, offsets, nullptr, aggBF);
  k_gemm4<2, false, true><<<GEMM_GRID, 256, 0, stream>>>(aggBF, W_u2, nullptr, nullptr,
                                                         b_u2, bufB, nullptr, sel, out,
                                                         nullptr);
}